// Round 7
// baseline (633.490 us; speedup 1.0000x reference)
//
#include <hip/hip_runtime.h>
#include <math.h>

#define N 256
#define BS 32
#define NB_ 8
#define EPS 1e-5f

// One block per batch, 1024 threads (16 waves/CU). Thread (ty,tx)=(tid>>5,tid&31)
// owns an 8x8 tile of M = L^T: rows [8ty,8ty+8), cols {4tx..+3} u {128+4tx..+3}
// (split-column mapping -> contiguous conflict-free panel accesses).
// fp64: pivot-block inversion + colsums. fp32: panels, R'=P*R, trailing GEMM.
// m[8][8]=64 VGPRs; all-fp32 hot loops keep us under the 128-reg cap (no spill).
__global__ __launch_bounds__(1024, 4) void mtt_fused(const float* __restrict__ x,
                                                     float* __restrict__ out) {
    constexpr int LDR = N + 8;
    __shared__ alignas(16) float  Rf[BS][LDR];     // row panel / x strip  33.8KB
    __shared__ alignas(16) float  CfT[BS][LDR];    // col panel, transposed 33.8KB
    __shared__ double Ps[BS][BS + 1];              // pivot block fp64      8.4KB
    __shared__ float  Pf[BS][BS + 1];              // pivot block fp32      4.2KB
    __shared__ double dsum[4][N];                  // colsum partials       8KB
    __shared__ float  sdx[N];                      // exp(x[i][i])          1KB
    __shared__ float  sdiag_f[N];
    __shared__ float  sroot_f[N];
    __shared__ int    indx[BS];

    const int tid = threadIdx.x;
    const int ty = tid >> 5, tx = tid & 31;        // ty 0..31
    const int R0  = ty << 3;
    const int c0a = tx << 2;
    const int c0b = 128 + (tx << 2);
    const float* xb = x + (size_t)blockIdx.x * N * N;
    float* ob = out + (size_t)blockIdx.x * N * N;

    float m[8][8];

    // ===================== PHASE 1: build M = L^T =====================
    double csacc = 0.0;
    const int tq = tid >> 8, jc = tid & 255;
#pragma unroll 1
    for (int s = 0; s < 8; ++s) {
        {   // coalesced strip load: x rows [32s,32s+32) -> Rf
            const int rl = tid >> 5, cl = (tid & 31) << 3;
            const float* src = &xb[(size_t)(32 * s + rl) * N + cl];
            *(float4*)&Rf[rl][cl]     = *(const float4*)&src[0];
            *(float4*)&Rf[rl][cl + 4] = *(const float4*)&src[4];
        }
        __syncthreads();
#pragma unroll
        for (int r = 0; r < 8; ++r)
            csacc += (double)expf(Rf[(tq << 3) + r][jc]);
        if (tid < 32) sdx[32 * s + tid] = expf(Rf[tid][32 * s + tid]);
        if ((tx >> 3) == s) {               // first-half cols: strips 0-3
            const int jb = (tx & 7) << 2;
#pragma unroll
            for (int cc = 0; cc < 4; ++cc)
#pragma unroll
                for (int r = 0; r < 8; ++r)
                    m[r][cc] = -(expf(Rf[jb + cc][R0 + r]) + EPS);
        }
        if (s >= 4 && (tx >> 3) == s - 4) { // second-half cols: strips 4-7
            const int jb = (tx & 7) << 2;
#pragma unroll
            for (int cc = 0; cc < 4; ++cc)
#pragma unroll
                for (int r = 0; r < 8; ++r)
                    m[r][4 + cc] = -(expf(Rf[jb + cc][R0 + r]) + EPS);
        }
        __syncthreads();
    }
    dsum[tq][jc] = csacc;
    __syncthreads();
    if (tid < N)
        dsum[0][tid] = dsum[0][tid] + dsum[1][tid] + dsum[2][tid] + dsum[3][tid];
    __syncthreads();
    // diag override: M[i][i] = colsum_i (i>0)
    if (ty < 16) {
#pragma unroll
        for (int r = 0; r < 8; ++r) {
            const int i = R0 + r;
            if (tx == ((ty << 1) + (r >> 2)) && i != 0)
                m[r][r & 3] =
                    (float)(dsum[0][i] - (double)sdx[i] + 255.0 * (double)EPS);
        }
    } else {
#pragma unroll
        for (int r = 0; r < 8; ++r) {
            const int i = R0 + r;
            if (tx == (((ty - 16) << 1) + (r >> 2)))
                m[r][4 + (r & 3)] =
                    (float)(dsum[0][i] - (double)sdx[i] + 255.0 * (double)EPS);
        }
    }
    if (tx == 0) {   // col-0 override: M[i][0] = exp(x[i][i])
#pragma unroll
        for (int r = 0; r < 8; ++r) m[r][0] = sdx[R0 + r];
    }

    // ===================== PHASE 2: blocked GJ (8 steps) =====================
#pragma unroll 1
    for (int kb = 0; kb < NB_; ++kb) {
        const bool rowOwner = (ty >> 2) == kb;
        const bool h0piv = (kb < 4) && ((tx >> 3) == kb);
        const bool h1piv = (kb >= 4) && ((tx >> 3) == kb - 4);
        const int lr = (ty & 3) << 3;           // local row base when rowOwner
        const int lc = (tx & 7) << 2;

        // ---- (a) stage panels from registers ----
        if (rowOwner) {
#pragma unroll
            for (int r = 0; r < 8; ++r) {
                *(float4*)&Rf[lr + r][c0a] =
                    make_float4(m[r][0], m[r][1], m[r][2], m[r][3]);
                *(float4*)&Rf[lr + r][c0b] =
                    make_float4(m[r][4], m[r][5], m[r][6], m[r][7]);
            }
        }
        if (h0piv) {
#pragma unroll
            for (int cc = 0; cc < 4; ++cc) {
                *(float4*)&CfT[lc + cc][R0] =
                    make_float4(m[0][cc], m[1][cc], m[2][cc], m[3][cc]);
                *(float4*)&CfT[lc + cc][R0 + 4] =
                    make_float4(m[4][cc], m[5][cc], m[6][cc], m[7][cc]);
            }
            if (rowOwner) {
#pragma unroll
                for (int r = 0; r < 8; ++r)
#pragma unroll
                    for (int cc = 0; cc < 4; ++cc)
                        Ps[lr + r][lc + cc] = (double)m[r][cc];
            }
        }
        if (h1piv) {
#pragma unroll
            for (int cc = 0; cc < 4; ++cc) {
                *(float4*)&CfT[lc + cc][R0] =
                    make_float4(m[0][4 + cc], m[1][4 + cc], m[2][4 + cc], m[3][4 + cc]);
                *(float4*)&CfT[lc + cc][R0 + 4] =
                    make_float4(m[4][4 + cc], m[5][4 + cc], m[6][4 + cc], m[7][4 + cc]);
            }
            if (rowOwner) {
#pragma unroll
                for (int r = 0; r < 8; ++r)
#pragma unroll
                    for (int cc = 0; cc < 4; ++cc)
                        Ps[lr + r][lc + cc] = (double)m[r][4 + cc];
            }
        }
        __syncthreads();

        // ---- (b) invert pivot block (fp64, partial pivot, butterfly search) ----
        {
            const int rr = tid & 31;    // search row for this lane (dup across waves)
            const int r = ty, c = tx;   // owned element of Ps
#pragma unroll 1
            for (int k2 = 0; k2 < BS; ++k2) {
                double v  = Ps[rr][k2];
                double av = (rr >= k2) ? fabs(v) : -1.0;
                int idx = rr;
#pragma unroll
                for (int off = 1; off < 64; off <<= 1) {
                    const double oav = __shfl_xor(av, off);
                    const double ov  = __shfl_xor(v, off);
                    const int    oi  = __shfl_xor(idx, off);
                    if (oav > av || (oav == av && oi < idx)) { av = oav; v = ov; idx = oi; }
                }
                const int p = idx;                 // identical in all waves (tie-break)
                const double pivinv = 1.0 / v;
                if (tid == 0) indx[k2] = p;
                const int sr = (r == k2) ? p : ((r == p) ? k2 : r);
                const double prow = Ps[p][c];
                const double aval = Ps[sr][c], scol = Ps[sr][k2];
                __syncthreads();
                const double srw = (c == k2) ? pivinv : prow * pivinv;
                const double base = (c == k2) ? 0.0 : aval;
                Ps[r][c] = (r == k2) ? srw : fma(-scol, srw, base);
                __syncthreads();
            }
            if (tid < 32) {   // column unscramble, thread tid owns row tid
                for (int k2 = BS - 1; k2 >= 0; --k2) {
                    const int p = indx[k2];
                    if (p != k2) {
                        double t = Ps[tid][k2];
                        Ps[tid][k2] = Ps[tid][p];
                        Ps[tid][p]  = t;
                    }
                }
            }
            __syncthreads();
            Pf[ty][tx] = (float)Ps[ty][tx];
            __syncthreads();
        }

        // ---- (c) R' = P * Rold (fp32); pivot cols <- P; Rf <- R' ----
        {
            float a0[8];
#pragma unroll
            for (int c = 0; c < 8; ++c) a0[c] = 0.f;
#pragma unroll 2
            for (int mm = 0; mm < BS; ++mm) {
                const float p0 = Pf[ty][mm];
                const float4 r0 = *(const float4*)&Rf[mm][c0a];
                const float4 r1 = *(const float4*)&Rf[mm][c0b];
                a0[0] = fmaf(p0, r0.x, a0[0]);
                a0[1] = fmaf(p0, r0.y, a0[1]);
                a0[2] = fmaf(p0, r0.z, a0[2]);
                a0[3] = fmaf(p0, r0.w, a0[3]);
                a0[4] = fmaf(p0, r1.x, a0[4]);
                a0[5] = fmaf(p0, r1.y, a0[5]);
                a0[6] = fmaf(p0, r1.z, a0[6]);
                a0[7] = fmaf(p0, r1.w, a0[7]);
            }
            if (h0piv) {
#pragma unroll
                for (int cc = 0; cc < 4; ++cc) a0[cc] = Pf[ty][lc + cc];
            }
            if (h1piv) {
#pragma unroll
                for (int cc = 0; cc < 4; ++cc) a0[4 + cc] = Pf[ty][lc + cc];
            }
            __syncthreads();
            *(float4*)&Rf[ty][c0a] = make_float4(a0[0], a0[1], a0[2], a0[3]);
            *(float4*)&Rf[ty][c0b] = make_float4(a0[4], a0[5], a0[6], a0[7]);
        }
        __syncthreads();

        // ---- (d) tile update ----
        if (rowOwner) {
#pragma unroll
            for (int r = 0; r < 8; ++r) {
                const float4 b0 = *(const float4*)&Rf[lr + r][c0a];
                const float4 b1 = *(const float4*)&Rf[lr + r][c0b];
                m[r][0] = b0.x; m[r][1] = b0.y; m[r][2] = b0.z; m[r][3] = b0.w;
                m[r][4] = b1.x; m[r][5] = b1.y; m[r][6] = b1.z; m[r][7] = b1.w;
            }
        } else {
            if (h0piv) {
#pragma unroll
                for (int r = 0; r < 8; ++r) {
                    m[r][0] = 0.f; m[r][1] = 0.f; m[r][2] = 0.f; m[r][3] = 0.f;
                }
            }
            if (h1piv) {
#pragma unroll
                for (int r = 0; r < 8; ++r) {
                    m[r][4] = 0.f; m[r][5] = 0.f; m[r][6] = 0.f; m[r][7] = 0.f;
                }
            }
#pragma unroll 2
            for (int mm = 0; mm < BS; ++mm) {
                const float4 rv0 = *(const float4*)&Rf[mm][c0a];
                const float4 rv1 = *(const float4*)&Rf[mm][c0b];
                const float4 cv0 = *(const float4*)&CfT[mm][R0];
                const float4 cv1 = *(const float4*)&CfT[mm][R0 + 4];
                {
                    const float cr = -cv0.x;
                    m[0][0] = fmaf(cr, rv0.x, m[0][0]); m[0][1] = fmaf(cr, rv0.y, m[0][1]);
                    m[0][2] = fmaf(cr, rv0.z, m[0][2]); m[0][3] = fmaf(cr, rv0.w, m[0][3]);
                    m[0][4] = fmaf(cr, rv1.x, m[0][4]); m[0][5] = fmaf(cr, rv1.y, m[0][5]);
                    m[0][6] = fmaf(cr, rv1.z, m[0][6]); m[0][7] = fmaf(cr, rv1.w, m[0][7]);
                }
                {
                    const float cr = -cv0.y;
                    m[1][0] = fmaf(cr, rv0.x, m[1][0]); m[1][1] = fmaf(cr, rv0.y, m[1][1]);
                    m[1][2] = fmaf(cr, rv0.z, m[1][2]); m[1][3] = fmaf(cr, rv0.w, m[1][3]);
                    m[1][4] = fmaf(cr, rv1.x, m[1][4]); m[1][5] = fmaf(cr, rv1.y, m[1][5]);
                    m[1][6] = fmaf(cr, rv1.z, m[1][6]); m[1][7] = fmaf(cr, rv1.w, m[1][7]);
                }
                {
                    const float cr = -cv0.z;
                    m[2][0] = fmaf(cr, rv0.x, m[2][0]); m[2][1] = fmaf(cr, rv0.y, m[2][1]);
                    m[2][2] = fmaf(cr, rv0.z, m[2][2]); m[2][3] = fmaf(cr, rv0.w, m[2][3]);
                    m[2][4] = fmaf(cr, rv1.x, m[2][4]); m[2][5] = fmaf(cr, rv1.y, m[2][5]);
                    m[2][6] = fmaf(cr, rv1.z, m[2][6]); m[2][7] = fmaf(cr, rv1.w, m[2][7]);
                }
                {
                    const float cr = -cv0.w;
                    m[3][0] = fmaf(cr, rv0.x, m[3][0]); m[3][1] = fmaf(cr, rv0.y, m[3][1]);
                    m[3][2] = fmaf(cr, rv0.z, m[3][2]); m[3][3] = fmaf(cr, rv0.w, m[3][3]);
                    m[3][4] = fmaf(cr, rv1.x, m[3][4]); m[3][5] = fmaf(cr, rv1.y, m[3][5]);
                    m[3][6] = fmaf(cr, rv1.z, m[3][6]); m[3][7] = fmaf(cr, rv1.w, m[3][7]);
                }
                {
                    const float cr = -cv1.x;
                    m[4][0] = fmaf(cr, rv0.x, m[4][0]); m[4][1] = fmaf(cr, rv0.y, m[4][1]);
                    m[4][2] = fmaf(cr, rv0.z, m[4][2]); m[4][3] = fmaf(cr, rv0.w, m[4][3]);
                    m[4][4] = fmaf(cr, rv1.x, m[4][4]); m[4][5] = fmaf(cr, rv1.y, m[4][5]);
                    m[4][6] = fmaf(cr, rv1.z, m[4][6]); m[4][7] = fmaf(cr, rv1.w, m[4][7]);
                }
                {
                    const float cr = -cv1.y;
                    m[5][0] = fmaf(cr, rv0.x, m[5][0]); m[5][1] = fmaf(cr, rv0.y, m[5][1]);
                    m[5][2] = fmaf(cr, rv0.z, m[5][2]); m[5][3] = fmaf(cr, rv0.w, m[5][3]);
                    m[5][4] = fmaf(cr, rv1.x, m[5][4]); m[5][5] = fmaf(cr, rv1.y, m[5][5]);
                    m[5][6] = fmaf(cr, rv1.z, m[5][6]); m[5][7] = fmaf(cr, rv1.w, m[5][7]);
                }
                {
                    const float cr = -cv1.z;
                    m[6][0] = fmaf(cr, rv0.x, m[6][0]); m[6][1] = fmaf(cr, rv0.y, m[6][1]);
                    m[6][2] = fmaf(cr, rv0.z, m[6][2]); m[6][3] = fmaf(cr, rv0.w, m[6][3]);
                    m[6][4] = fmaf(cr, rv1.x, m[6][4]); m[6][5] = fmaf(cr, rv1.y, m[6][5]);
                    m[6][6] = fmaf(cr, rv1.z, m[6][6]); m[6][7] = fmaf(cr, rv1.w, m[6][7]);
                }
                {
                    const float cr = -cv1.w;
                    m[7][0] = fmaf(cr, rv0.x, m[7][0]); m[7][1] = fmaf(cr, rv0.y, m[7][1]);
                    m[7][2] = fmaf(cr, rv0.z, m[7][2]); m[7][3] = fmaf(cr, rv0.w, m[7][3]);
                    m[7][4] = fmaf(cr, rv1.x, m[7][4]); m[7][5] = fmaf(cr, rv1.y, m[7][5]);
                    m[7][6] = fmaf(cr, rv1.z, m[7][6]); m[7][7] = fmaf(cr, rv1.w, m[7][7]);
                }
            }
        }
        __syncthreads();
    }

    // ===================== PHASE 3: epilogue =====================
    if (ty < 16) {
#pragma unroll
        for (int r = 0; r < 8; ++r) {
            const int i = R0 + r;
            if (tx == ((ty << 1) + (r >> 2))) sdiag_f[i] = m[r][r & 3];
        }
    } else {
#pragma unroll
        for (int r = 0; r < 8; ++r) {
            const int i = R0 + r;
            if (tx == (((ty - 16) << 1) + (r >> 2))) sdiag_f[i] = m[r][4 + (r & 3)];
        }
    }
    if (ty == 0) {
        *(float4*)&sroot_f[c0a] = make_float4(m[0][0], m[0][1], m[0][2], m[0][3]);
        *(float4*)&sroot_f[c0b] = make_float4(m[0][4], m[0][5], m[0][6], m[0][7]);
    }
    __syncthreads();

    float sd[8];
    {
        const float4 s0 = *(const float4*)&sdiag_f[c0a];
        const float4 s1 = *(const float4*)&sdiag_f[c0b];
        sd[0] = s0.x; sd[1] = s0.y; sd[2] = s0.z; sd[3] = s0.w;
        sd[4] = s1.x; sd[5] = s1.y; sd[6] = s1.z; sd[7] = s1.w;
    }
#pragma unroll
    for (int r = 0; r < 8; ++r) {
        const int a = R0 + r;
        const float4 x0 = *(const float4*)&xb[(size_t)a * N + c0a];
        const float4 x1 = *(const float4*)&xb[(size_t)a * N + c0b];
        const float xv[8] = {x0.x, x0.y, x0.z, x0.w, x1.x, x1.y, x1.z, x1.w};
        const float rt = sroot_f[a];
        float ov[8];
#pragma unroll
        for (int c = 0; c < 8; ++c) {
            const int b_ = (c < 4) ? (c0a + c) : (c0b + (c - 4));
            const float e = expf(xv[c]);
            float o = (b_ == 0) ? 0.0f : e * sd[c];
            if (a != 0) o -= e * m[r][c];          // e * inv^T[a][b]
            if (a == b_) o += e * rt;              // e * inv[a][0]
            ov[c] = o;
        }
        *(float4*)&ob[(size_t)a * N + c0a] = make_float4(ov[0], ov[1], ov[2], ov[3]);
        *(float4*)&ob[(size_t)a * N + c0b] = make_float4(ov[4], ov[5], ov[6], ov[7]);
    }
}

extern "C" void kernel_launch(void* const* d_in, const int* in_sizes, int n_in,
                              void* d_out, int out_size, void* d_ws, size_t ws_size,
                              hipStream_t stream) {
    const float* x = (const float*)d_in[0];
    float* out = (float*)d_out;
    mtt_fused<<<256, 1024, 0, stream>>>(x, out);
}

// Round 8
// 443.538 us; speedup vs baseline: 1.4283x; 1.4283x over previous
//
#include <hip/hip_runtime.h>
#include <math.h>

#define N 256
#define BS 32
#define NB_ 8
#define EPS 1e-5f

// One block per batch, 512 threads. Thread (ty,tx)=(tid>>5,tid&31) owns a
// 16x8 tile of M = L^T: rows [16ty,16ty+16), cols {4tx..+3} u {128+4tx..+3}.
// Pivot-block inversion: wave 0 only, register-resident (lane l&31 = row,
// l>>5 = col half, 16 fp64 regs), fully unrolled, shuffle-based, ZERO
// barriers inside (was 512 barriers in round 6). Panels ping-pong RfA->RfB.
__global__ __launch_bounds__(512, 2) void mtt_fused(const float* __restrict__ x,
                                                    float* __restrict__ out) {
    constexpr int LDR = N + 8;
    __shared__ alignas(16) float  RfA[BS][LDR];    // row panel (old) / x strip
    __shared__ alignas(16) float  RfB[BS][LDR];    // row panel (new R')
    __shared__ alignas(16) float  CfT[BS][LDR];    // col panel, transposed
    __shared__ float  Pf[BS][BS + 1];              // inverted pivot block fp32
    __shared__ double dsum[2][N];                  // colsum partials
    __shared__ float  sdx[N];                      // exp(x[i][i])
    __shared__ float  sdiag_f[N];
    __shared__ float  sroot_f[N];
    __shared__ int    indx[BS];

    const int tid = threadIdx.x;
    const int ty = tid >> 5, tx = tid & 31;        // ty 0..15
    const int R0  = ty << 4;
    const int c0a = tx << 2;
    const int c0b = 128 + (tx << 2);
    const float* xb = x + (size_t)blockIdx.x * N * N;
    float* ob = out + (size_t)blockIdx.x * N * N;

    float m[16][8];

    // ===================== PHASE 1: build M = L^T =====================
    double csacc = 0.0;
    const int tq = tid >> 8, jc = tid & 255;
#pragma unroll 1
    for (int s = 0; s < 8; ++s) {
        {   // coalesced strip load: x rows [32s,32s+32) -> RfA
            const int rl = tid >> 4, cl = (tid & 15) << 4;
            const float* src = &xb[(size_t)(32 * s + rl) * N + cl];
            *(float4*)&RfA[rl][cl]      = *(const float4*)&src[0];
            *(float4*)&RfA[rl][cl + 4]  = *(const float4*)&src[4];
            *(float4*)&RfA[rl][cl + 8]  = *(const float4*)&src[8];
            *(float4*)&RfA[rl][cl + 12] = *(const float4*)&src[12];
        }
        __syncthreads();
#pragma unroll
        for (int r = 0; r < 16; ++r)
            csacc += (double)expf(RfA[(tq << 4) + r][jc]);
        if (tid < 32) sdx[32 * s + tid] = expf(RfA[tid][32 * s + tid]);
        if ((tx >> 3) == s) {               // first-half cols: strips 0-3
            const int jb = (tx & 7) << 2;
#pragma unroll
            for (int cc = 0; cc < 4; ++cc)
#pragma unroll
                for (int r = 0; r < 16; ++r)
                    m[r][cc] = -(expf(RfA[jb + cc][R0 + r]) + EPS);
        }
        if (s >= 4 && (tx >> 3) == s - 4) { // second-half cols: strips 4-7
            const int jb = (tx & 7) << 2;
#pragma unroll
            for (int cc = 0; cc < 4; ++cc)
#pragma unroll
                for (int r = 0; r < 16; ++r)
                    m[r][4 + cc] = -(expf(RfA[jb + cc][R0 + r]) + EPS);
        }
        __syncthreads();
    }
    dsum[tq][jc] = csacc;
    __syncthreads();
    if (tid < N) dsum[0][tid] += dsum[1][tid];
    __syncthreads();
    // diag override: M[i][i] = colsum_i (i>0)
    if (ty < 8) {
#pragma unroll
        for (int r = 0; r < 16; ++r) {
            const int i = R0 + r;
            if (tx == (i >> 2) && i != 0)
                m[r][r & 3] =
                    (float)(dsum[0][i] - (double)sdx[i] + 255.0 * (double)EPS);
        }
    } else {
#pragma unroll
        for (int r = 0; r < 16; ++r) {
            const int i = R0 + r;
            if (tx == ((i - 128) >> 2))
                m[r][4 + (r & 3)] =
                    (float)(dsum[0][i] - (double)sdx[i] + 255.0 * (double)EPS);
        }
    }
    if (tx == 0) {   // col-0 override: M[i][0] = exp(x[i][i])
#pragma unroll
        for (int r = 0; r < 16; ++r) m[r][0] = sdx[R0 + r];
    }

    // ===================== PHASE 2: blocked GJ (8 steps) =====================
#pragma unroll 1
    for (int kb = 0; kb < NB_; ++kb) {
        const int k0 = kb * BS;
        const bool rowOwner = (ty >> 1) == kb;
        const bool h0piv = (kb < 4) && ((tx >> 3) == kb);
        const bool h1piv = (kb >= 4) && ((tx >> 3) == kb - 4);
        const int lr = (ty - (kb << 1)) << 4;   // 0 or 16 when rowOwner
        const int lc = (tx & 7) << 2;

        // ---- (a) stage panels from registers ----
        if (rowOwner) {
#pragma unroll
            for (int r = 0; r < 16; ++r) {
                *(float4*)&RfA[lr + r][c0a] =
                    make_float4(m[r][0], m[r][1], m[r][2], m[r][3]);
                *(float4*)&RfA[lr + r][c0b] =
                    make_float4(m[r][4], m[r][5], m[r][6], m[r][7]);
            }
        }
        if (h0piv) {
#pragma unroll
            for (int cc = 0; cc < 4; ++cc) {
                *(float4*)&CfT[lc + cc][R0]      = make_float4(m[0][cc],  m[1][cc],  m[2][cc],  m[3][cc]);
                *(float4*)&CfT[lc + cc][R0 + 4]  = make_float4(m[4][cc],  m[5][cc],  m[6][cc],  m[7][cc]);
                *(float4*)&CfT[lc + cc][R0 + 8]  = make_float4(m[8][cc],  m[9][cc],  m[10][cc], m[11][cc]);
                *(float4*)&CfT[lc + cc][R0 + 12] = make_float4(m[12][cc], m[13][cc], m[14][cc], m[15][cc]);
            }
        }
        if (h1piv) {
#pragma unroll
            for (int cc = 0; cc < 4; ++cc) {
                *(float4*)&CfT[lc + cc][R0]      = make_float4(m[0][4+cc],  m[1][4+cc],  m[2][4+cc],  m[3][4+cc]);
                *(float4*)&CfT[lc + cc][R0 + 4]  = make_float4(m[4][4+cc],  m[5][4+cc],  m[6][4+cc],  m[7][4+cc]);
                *(float4*)&CfT[lc + cc][R0 + 8]  = make_float4(m[8][4+cc],  m[9][4+cc],  m[10][4+cc], m[11][4+cc]);
                *(float4*)&CfT[lc + cc][R0 + 12] = make_float4(m[12][4+cc], m[13][4+cc], m[14][4+cc], m[15][4+cc]);
            }
        }
        __syncthreads();   // bar1: panels staged

        // ---- (b) wave-0 register-resident fp64 inversion (no barriers) ----
        if (tid < 64) {
            const int l = tid;
            const int row = l & 31;
            const int h = l >> 5;          // column half: cols 16h..16h+15
            const int hb = h << 5;
            double p[16];
            // pivot block input = col panel rows k0..k0+31 (fp32 -> fp64)
#pragma unroll
            for (int j = 0; j < 16; ++j)
                p[j] = (double)CfT[(h << 4) + j][k0 + row];

#pragma unroll
            for (int k2 = 0; k2 < BS; ++k2) {
                const int hk2 = k2 >> 4, jk2 = k2 & 15;
                // --- pivot search on col k2, rows >= k2 (64-lane butterfly) ---
                const double cand = p[jk2];
                double av = (h == hk2 && row >= k2) ? fabs(cand) : -1.0;
                double vv = cand;
                int idx = row;
#pragma unroll
                for (int off = 1; off < 64; off <<= 1) {
                    const double oav = __shfl_xor(av, off);
                    const double ovv = __shfl_xor(vv, off);
                    const int    oi  = __shfl_xor(idx, off);
                    if (oav > av || (oav == av && oi < idx)) { av = oav; vv = ovv; idx = oi; }
                }
                const double pivinv = 1.0 / vv;
                if (l == 0) indx[k2] = idx;
                // --- physical row swap k2 <-> idx (register exchange) ---
                const int prt = (row == k2) ? idx : ((row == idx) ? k2 : row);
                const int sl = prt + hb;
#pragma unroll
                for (int j = 0; j < 16; ++j) p[j] = __shfl(p[j], sl);
                // --- eliminate ---
                const double scol = __shfl(p[jk2], row + (hk2 << 5)); // (row,k2)
                const int pl = k2 + hb;
                const bool isPivRow = (row == k2);
#pragma unroll
                for (int j = 0; j < 16; ++j) {
                    const double prow = __shfl(p[j], pl);             // pre-scale
                    const bool isK2col = (h == hk2) && (j == jk2);
                    const double srw  = isK2col ? pivinv : prow * pivinv;
                    const double base = isK2col ? 0.0 : p[j];
                    p[j] = isPivRow ? srw : fma(-scol, srw, base);
                }
            }
            // write fp32 pivot inverse
#pragma unroll
            for (int j = 0; j < 16; ++j)
                Pf[row][(h << 4) + j] = (float)p[j];
            // column unscramble (same wave: LDS ops in program order)
            if (l < 32) {
#pragma unroll 1
                for (int k2 = BS - 1; k2 >= 0; --k2) {
                    const int pp = indx[k2];
                    if (pp != k2) {
                        const float t = Pf[l][k2];
                        Pf[l][k2] = Pf[l][pp];
                        Pf[l][pp] = t;
                    }
                }
            }
        }
        __syncthreads();   // bar2: Pf ready

        // ---- (c) R' = P * Rold (fp32): read RfA, write RfB ----
        {
            float a0[8], a1[8];
#pragma unroll
            for (int c = 0; c < 8; ++c) { a0[c] = 0.f; a1[c] = 0.f; }
#pragma unroll 2
            for (int mm = 0; mm < BS; ++mm) {
                const float p0 = Pf[ty][mm];
                const float p1 = Pf[ty + 16][mm];
                const float4 r0 = *(const float4*)&RfA[mm][c0a];
                const float4 r1 = *(const float4*)&RfA[mm][c0b];
                a0[0] = fmaf(p0, r0.x, a0[0]);  a1[0] = fmaf(p1, r0.x, a1[0]);
                a0[1] = fmaf(p0, r0.y, a0[1]);  a1[1] = fmaf(p1, r0.y, a1[1]);
                a0[2] = fmaf(p0, r0.z, a0[2]);  a1[2] = fmaf(p1, r0.z, a1[2]);
                a0[3] = fmaf(p0, r0.w, a0[3]);  a1[3] = fmaf(p1, r0.w, a1[3]);
                a0[4] = fmaf(p0, r1.x, a0[4]);  a1[4] = fmaf(p1, r1.x, a1[4]);
                a0[5] = fmaf(p0, r1.y, a0[5]);  a1[5] = fmaf(p1, r1.y, a1[5]);
                a0[6] = fmaf(p0, r1.z, a0[6]);  a1[6] = fmaf(p1, r1.z, a1[6]);
                a0[7] = fmaf(p0, r1.w, a0[7]);  a1[7] = fmaf(p1, r1.w, a1[7]);
            }
            if (h0piv) {
#pragma unroll
                for (int cc = 0; cc < 4; ++cc) {
                    a0[cc] = Pf[ty][lc + cc];
                    a1[cc] = Pf[ty + 16][lc + cc];
                }
            }
            if (h1piv) {
#pragma unroll
                for (int cc = 0; cc < 4; ++cc) {
                    a0[4 + cc] = Pf[ty][lc + cc];
                    a1[4 + cc] = Pf[ty + 16][lc + cc];
                }
            }
            *(float4*)&RfB[ty][c0a]      = make_float4(a0[0], a0[1], a0[2], a0[3]);
            *(float4*)&RfB[ty][c0b]      = make_float4(a0[4], a0[5], a0[6], a0[7]);
            *(float4*)&RfB[ty + 16][c0a] = make_float4(a1[0], a1[1], a1[2], a1[3]);
            *(float4*)&RfB[ty + 16][c0b] = make_float4(a1[4], a1[5], a1[6], a1[7]);
        }
        __syncthreads();   // bar3: R' ready

        // ---- (d) tile update: m -= C * R'  (reads RfB + CfT) ----
        if (rowOwner) {
#pragma unroll
            for (int r = 0; r < 16; ++r) {
                const float4 b0 = *(const float4*)&RfB[lr + r][c0a];
                const float4 b1 = *(const float4*)&RfB[lr + r][c0b];
                m[r][0] = b0.x; m[r][1] = b0.y; m[r][2] = b0.z; m[r][3] = b0.w;
                m[r][4] = b1.x; m[r][5] = b1.y; m[r][6] = b1.z; m[r][7] = b1.w;
            }
        } else {
            if (h0piv) {
#pragma unroll
                for (int r = 0; r < 16; ++r) {
                    m[r][0] = 0.f; m[r][1] = 0.f; m[r][2] = 0.f; m[r][3] = 0.f;
                }
            }
            if (h1piv) {
#pragma unroll
                for (int r = 0; r < 16; ++r) {
                    m[r][4] = 0.f; m[r][5] = 0.f; m[r][6] = 0.f; m[r][7] = 0.f;
                }
            }
#pragma unroll 2
            for (int mm = 0; mm < BS; ++mm) {
                const float4 rv0 = *(const float4*)&RfB[mm][c0a];
                const float4 rv1 = *(const float4*)&RfB[mm][c0b];
                const float4 cv0 = *(const float4*)&CfT[mm][R0];
                const float4 cv1 = *(const float4*)&CfT[mm][R0 + 4];
                const float4 cv2 = *(const float4*)&CfT[mm][R0 + 8];
                const float4 cv3 = *(const float4*)&CfT[mm][R0 + 12];
                const float cc16[16] = {cv0.x, cv0.y, cv0.z, cv0.w,
                                        cv1.x, cv1.y, cv1.z, cv1.w,
                                        cv2.x, cv2.y, cv2.z, cv2.w,
                                        cv3.x, cv3.y, cv3.z, cv3.w};
#pragma unroll
                for (int r = 0; r < 16; ++r) {
                    const float cr = -cc16[r];
                    m[r][0] = fmaf(cr, rv0.x, m[r][0]);
                    m[r][1] = fmaf(cr, rv0.y, m[r][1]);
                    m[r][2] = fmaf(cr, rv0.z, m[r][2]);
                    m[r][3] = fmaf(cr, rv0.w, m[r][3]);
                    m[r][4] = fmaf(cr, rv1.x, m[r][4]);
                    m[r][5] = fmaf(cr, rv1.y, m[r][5]);
                    m[r][6] = fmaf(cr, rv1.z, m[r][6]);
                    m[r][7] = fmaf(cr, rv1.w, m[r][7]);
                }
            }
        }
        __syncthreads();   // bar4: CfT/RfA free for next step
    }

    // ===================== PHASE 3: epilogue =====================
    if (ty < 8) {
#pragma unroll
        for (int r = 0; r < 16; ++r) {
            const int i = R0 + r;
            if (tx == (i >> 2)) sdiag_f[i] = m[r][r & 3];
        }
    } else {
#pragma unroll
        for (int r = 0; r < 16; ++r) {
            const int i = R0 + r;
            if (tx == ((i - 128) >> 2)) sdiag_f[i] = m[r][4 + (r & 3)];
        }
    }
    if (ty == 0) {
        *(float4*)&sroot_f[c0a] = make_float4(m[0][0], m[0][1], m[0][2], m[0][3]);
        *(float4*)&sroot_f[c0b] = make_float4(m[0][4], m[0][5], m[0][6], m[0][7]);
    }
    __syncthreads();

    float sd[8];
    {
        const float4 s0 = *(const float4*)&sdiag_f[c0a];
        const float4 s1 = *(const float4*)&sdiag_f[c0b];
        sd[0] = s0.x; sd[1] = s0.y; sd[2] = s0.z; sd[3] = s0.w;
        sd[4] = s1.x; sd[5] = s1.y; sd[6] = s1.z; sd[7] = s1.w;
    }
#pragma unroll
    for (int r = 0; r < 16; ++r) {
        const int a = R0 + r;
        const float4 x0 = *(const float4*)&xb[(size_t)a * N + c0a];
        const float4 x1 = *(const float4*)&xb[(size_t)a * N + c0b];
        const float xv[8] = {x0.x, x0.y, x0.z, x0.w, x1.x, x1.y, x1.z, x1.w};
        const float rt = sroot_f[a];
        float ov[8];
#pragma unroll
        for (int c = 0; c < 8; ++c) {
            const int b_ = (c < 4) ? (c0a + c) : (c0b + (c - 4));
            const float e = expf(xv[c]);
            float o = (b_ == 0) ? 0.0f : e * sd[c];
            if (a != 0) o -= e * m[r][c];          // e * inv^T[a][b]
            if (a == b_) o += e * rt;              // e * inv[a][0]
            ov[c] = o;
        }
        *(float4*)&ob[(size_t)a * N + c0a] = make_float4(ov[0], ov[1], ov[2], ov[3]);
        *(float4*)&ob[(size_t)a * N + c0b] = make_float4(ov[4], ov[5], ov[6], ov[7]);
    }
}

extern "C" void kernel_launch(void* const* d_in, const int* in_sizes, int n_in,
                              void* d_out, int out_size, void* d_ws, size_t ws_size,
                              hipStream_t stream) {
    const float* x = (const float*)d_in[0];
    float* out = (float*)d_out;
    mtt_fused<<<256, 512, 0, stream>>>(x, out);
}